// Round 5
// baseline (70.510 us; speedup 1.0000x reference)
//
#include <hip/hip_runtime.h>

#define NUM_BINS 1025
#define NBLK 2048
#define BLOCK 256
#define SCALEF 1024.0f
#define INV_SCALE 0.0009765625f   // 2^-10

// Stage 1: per-block signed i32 LDS histogram via integer DS atomics,
// flushed with one global int atomicAdd per bin into bins_acc (L2-resident).
__global__ __launch_bounds__(BLOCK) void hist_kernel(
    const float* __restrict__ od, const int* __restrict__ om,
    const float* __restrict__ pd, const int* __restrict__ nm,
    int* __restrict__ bins_acc, int n)
{
    __shared__ int lh[NUM_BINS];
    const int tid = threadIdx.x;
    for (int b = tid; b < NUM_BINS; b += BLOCK) lh[b] = 0;
    __syncthreads();

    const int n4 = n >> 2;
    const float4* od4 = (const float4*)od;
    const int4*   om4 = (const int4*)om;
    const float4* pd4 = (const float4*)pd;
    const int4*   nm4 = (const int4*)nm;

    const int stride = gridDim.x * BLOCK;
    int i = blockIdx.x * BLOCK + tid;
    if (i < n4) {
        float4 d = od4[i]; int4 m = om4[i];
        float4 e = pd4[i]; int4 q = nm4[i];
        for (;;) {
            const int j = i + stride;
            const bool more = j < n4;
            float4 d2, e2; int4 m2, q2;
            if (more) { d2 = od4[j]; m2 = om4[j]; e2 = pd4[j]; q2 = nm4[j]; }
            atomicAdd(&lh[m.x],  __float2int_rn(d.x * SCALEF));
            atomicAdd(&lh[m.y],  __float2int_rn(d.y * SCALEF));
            atomicAdd(&lh[m.z],  __float2int_rn(d.z * SCALEF));
            atomicAdd(&lh[m.w],  __float2int_rn(d.w * SCALEF));
            atomicAdd(&lh[q.x], -__float2int_rn(e.x * SCALEF));
            atomicAdd(&lh[q.y], -__float2int_rn(e.y * SCALEF));
            atomicAdd(&lh[q.z], -__float2int_rn(e.z * SCALEF));
            atomicAdd(&lh[q.w], -__float2int_rn(e.w * SCALEF));
            if (!more) break;
            d = d2; m = m2; e = e2; q = q2; i = j;
        }
    }
    // scalar tail (n % 4) — empty for 4096x4096
    if (blockIdx.x == 0 && tid == 0) {
        for (int k = n4 << 2; k < n; ++k) {
            atomicAdd(&lh[om[k]],  __float2int_rn(od[k] * SCALEF));
            atomicAdd(&lh[nm[k]], -__float2int_rn(pd[k] * SCALEF));
        }
    }
    __syncthreads();

    for (int b = tid; b < NUM_BINS; b += BLOCK) {
        const int v = lh[b];
        if (v != 0) atomicAdd(&bins_acc[b], v);
    }
}

// Stage 2: single block — abs of each bin total, block-reduce sum, write out.
__global__ __launch_bounds__(1024) void final_kernel(
    const int* __restrict__ bins_acc, float* __restrict__ out)
{
    const int tid = threadIdx.x;
    float v = 0.0f;
    for (int b = tid; b < NUM_BINS; b += 1024)
        v += fabsf((float)bins_acc[b]);

    for (int off = 32; off > 0; off >>= 1)
        v += __shfl_down(v, off, 64);

    __shared__ float wsum[16];
    const int wave = tid >> 6;
    const int lane = tid & 63;
    if (lane == 0) wsum[wave] = v;
    __syncthreads();
    if (tid == 0) {
        float t = 0.0f;
        #pragma unroll
        for (int w = 0; w < 16; ++w) t += wsum[w];
        out[0] = t * INV_SCALE;
    }
}

extern "C" void kernel_launch(void* const* d_in, const int* in_sizes, int n_in,
                              void* d_out, int out_size, void* d_ws, size_t ws_size,
                              hipStream_t stream) {
    const float* od = (const float*)d_in[0];   // origin_density
    const int*   om = (const int*)d_in[1];     // origin_mask
    const float* pd = (const float*)d_in[2];   // pre_density
    const int*   nm = (const int*)d_in[3];     // new_mask
    float* out    = (float*)d_out;
    int* bins_acc = (int*)d_ws;                // NUM_BINS * 4 = 4.1 KB
    const int n = in_sizes[0];

    hipMemsetAsync(bins_acc, 0, NUM_BINS * sizeof(int), stream);
    hist_kernel<<<NBLK, BLOCK, 0, stream>>>(od, om, pd, nm, bins_acc, n);
    final_kernel<<<1, 1024, 0, stream>>>(bins_acc, out);
}